// Round 10
// baseline (191.265 us; speedup 1.0000x reference)
//
#include <hip/hip_runtime.h>
#include <math.h>

// FDTD2DLayer: out = (2*Re(scan(lam2, x@B^T * scaling))) @ C^T + x*D
// m1 == 0, m3 == conj(m2) (sBu real, lam3 = conj(lam2)) => p = 2*Re(m2).
// GEMMs: bf16 2-way-split MFMA, 3-product (hh+hl+lh), fp32 accumulate.
// R8 measured: GEMMs <=40.6us each but ~58% of K-step cycles are barrier/
// vmcnt(0)-drain stalls. This round: depth-2 counted-vmcnt pipeline (T3+T4),
// 3-buffer LDS ring, raw s_barrier (never vmcnt(0) in main loop).

#define SEQ 8192
#define HDIM 512
#define GS 32
#define G 1024
#define CHUNK 128
#define NCH (SEQ / CHUNK)

typedef unsigned short u16;
typedef unsigned int u32;
typedef __attribute__((ext_vector_type(8))) short short8;  // 8 bf16 = 4 VGPR
typedef __attribute__((ext_vector_type(4))) float f32x4;   // MFMA C/D

#define AS1 __attribute__((address_space(1)))
#define AS3 __attribute__((address_space(3)))

__device__ __forceinline__ float softplusf(float z) {
    return fmaxf(z, 0.0f) + log1pf(expf(-fabsf(z)));
}
__device__ __forceinline__ float clipf(float v, float lo, float hi) {
    return fminf(fmaxf(v, lo), hi);
}
// split fp32 -> bf16 hi + bf16 lo; f ≈ hi + lo, |err| <= ~2^-17|f|
__device__ __forceinline__ void split2(float f, u16& h, u16& l) {
    u32 b = __float_as_uint(f);
    u32 hb = (b + 0x8000u) & 0xffff0000u;
    h = (u16)(hb >> 16);
    float r = f - __uint_as_float(hb);          // exact in fp32
    l = (u16)((__float_as_uint(r) + 0x8000u) >> 16);
}
// counted vmcnt waits (immediates only)
template<int N> __device__ __forceinline__ void waitv() {
    if constexpr (N == 0)       asm volatile("s_waitcnt vmcnt(0)" ::: "memory");
    else if constexpr (N == 6)  asm volatile("s_waitcnt vmcnt(6)" ::: "memory");
    else if constexpr (N == 8)  asm volatile("s_waitcnt vmcnt(8)" ::: "memory");
    else if constexpr (N == 12) asm volatile("s_waitcnt vmcnt(12)" ::: "memory");
    else if constexpr (N == 16) asm volatile("s_waitcnt vmcnt(16)" ::: "memory");
}

// ---------------------------------------------------------------- params (G threads)
__global__ void params_kernel(const float* __restrict__ c,
                              const float* __restrict__ kp_diag,
                              const float* __restrict__ k_diag,
                              const float* __restrict__ dt_matrix,
                              float* __restrict__ lam_re, float* __restrict__ lam_im,
                              float* __restrict__ scal,
                              float* __restrict__ lamC_re, float* __restrict__ lamC_im) {
    int g = blockIdx.x * blockDim.x + threadIdx.x;
    if (g >= G) return;
    float dt = clipf(expf(dt_matrix[g]), 0.1f, 5.0f);
    float max_c = 0.7f / dt;
    float c_pos = clipf(softplusf(c[g]), 0.01f, 0.9f * max_c);

    float kp_base = 0.0f, k_base = 0.0f;
    if (g % (GS + 1) == 0) {
        int d = g / (GS + 1);
        float kp_d = clipf(softplusf(kp_diag[d]), 1e-4f, 0.2f);
        kp_base = clipf(softplusf(kp_d), 1e-4f, 0.5f);
        float k_d = clipf(softplusf(k_diag[d]), 1e-4f, 0.2f);
        k_base = clipf(softplusf(k_d), 1e-4f, 0.5f);
    }
    float kp_full = clipf(softplusf(kp_base), 1e-4f, 0.5f);
    float k_full  = clipf(softplusf(k_base),  1e-4f, 0.5f);

    float d1 = fmaxf(1.0f + dt * k_full, 0.1f);
    float d2 = fmaxf(1.0f + dt * kp_full, 0.1f);
    float real_part = 0.5f * (1.0f / d2 + 1.0f / d1);
    float c_safe = clipf(c_pos, 0.01f, 1.0f);
    const float xi = 1.5707963267948966f;
    float imag_part = clipf(c_safe * dt * xi / sqrtf(fmaxf(d1 * d2, 1e-6f)), -10.0f, 10.0f);

    lam_re[g] = real_part;
    lam_im[g] = imag_part;
    scal[g] = 1.0f / (1.0f + dt * kp_full);

    float ar = real_part, ai = imag_part;       // lambda^CHUNK by squaring
#pragma unroll
    for (int s = 0; s < 7; ++s) {
        float nr = ar * ar - ai * ai;
        float ni = 2.0f * ar * ai;
        ar = nr; ai = ni;
    }
    lamC_re[g] = ar; lamC_im[g] = ai;
}

// ---------------------------------------------------------------- fused fp32 -> (bf16h, bf16l) for x, B, Cm
#define N4X (SEQ * HDIM / 4)
#define N4B (G * HDIM / 4)
#define N4C (HDIM * G / 4)
__global__ __launch_bounds__(256)
void split_all(const float* __restrict__ x,  u16* __restrict__ xh,  u16* __restrict__ xl,
               const float* __restrict__ B,  u16* __restrict__ Bh,  u16* __restrict__ Bl,
               const float* __restrict__ Cm, u16* __restrict__ Ch,  u16* __restrict__ Cl) {
    int stride = gridDim.x * 256;
    for (int i = blockIdx.x * 256 + threadIdx.x; i < N4X + N4B + N4C; i += stride) {
        const float* in; u16* hi; u16* lo; int j = i;
        if (j < N4X) { in = x; hi = xh; lo = xl; }
        else if (j < N4X + N4B) { j -= N4X; in = B; hi = Bh; lo = Bl; }
        else { j -= N4X + N4B; in = Cm; hi = Ch; lo = Cl; }
        float4 v = ((const float4*)in)[j];
        ushort4 h, l;
        split2(v.x, h.x, l.x); split2(v.y, h.y, l.y);
        split2(v.z, h.z, l.z); split2(v.w, h.w, l.w);
        ((ushort4*)hi)[j] = h;
        ((ushort4*)lo)[j] = l;
    }
}

// ---------------------------------------------------------------- split-bf16 MFMA GEMM
// Cout[M,N] = (Ah+Al)[M,K] * (Bh+Bl)[N,K]^T   (bf16 row-major, K-contig)
// 2x2 waves of WMxWN; BK=32; depth-2 counted-vmcnt pipeline over a 3-buffer
// LDS ring: stage(t+2); vmcnt(2L) [t landed, t+1/t+2 in flight]; s_barrier;
// ds_read+MFMA; s_barrier. LDS swizzle (R7: 0 bank conflicts): physical 16B
// slot = logical ^ ((row>>1)&3), applied on global source + ds_read index,
// LDS dest linear (rule #21). T1 XCD swizzle on the block id (R8).
template<int BM, int BN, int WM, int WN, bool SCALE_EPI>
__global__ __launch_bounds__(256, 2)
void gemm_split(const u16* __restrict__ Ah, const u16* __restrict__ Al,
                const u16* __restrict__ Bh, const u16* __restrict__ Bl,
                float* __restrict__ Cout, int M, int N, int K,
                const float* __restrict__ scal,
                const float* __restrict__ xres, const float* __restrict__ Dv) {
    constexpr int MI = WM / 16, NI = WN / 16;
    constexpr int ACH = BM / 16, BCH = BN / 16;            // 1KB chunks (16 rows x 32 u16)
    constexpr int oAh = 0, oAl = BM * 32;
    constexpr int oBh = 2 * BM * 32, oBl = 2 * BM * 32 + BN * 32;
    constexpr int BUFS = 2 * BM * 32 + 2 * BN * 32;        // u16 per buffer
    constexpr int LPW = (ACH + BCH) / 2;                   // global_load_lds per wave per stage
    __shared__ __align__(16) u16 sm[3][BUFS];

    const int tid = threadIdx.x;
    const int lane = tid & 63, wid = tid >> 6;
    const int wrow = wid >> 1, wcol = wid & 1;
    const int lr = lane & 15, lg = lane >> 4;

    // T1: bijective XCD swizzle (nwg % 8 == 0 for both grids: 512)
    const int flat = blockIdx.y * gridDim.x + blockIdx.x;
    const int cpx = (gridDim.x * gridDim.y) >> 3;
    const int swz = (flat & 7) * cpx + (flat >> 3);
    const int m0 = (swz / gridDim.x) * BM, n0 = (swz % gridDim.x) * BN;

    const u16* gbs[4]   = {Ah, Al, Bh, Bl};
    const int  nchs[4]  = {ACH, ACH, BCH, BCH};
    const int  row0s[4] = {m0, m0, n0, n0};
    const int  ofss[4]  = {oAh, oAl, oBh, oBl};

    const int srow = lane >> 2;        // row-in-chunk 0..15
    const int shp  = lane & 3;         // physical 16B slot in row

    auto stage = [&](int buf, int kt) {
#pragma unroll
        for (int a = 0; a < 4; ++a) {
            for (int c = wid; c < nchs[a]; c += 4) {
                int r = c * 16 + srow;
                int h = shp ^ ((r >> 1) & 3);              // inverse swizzle on source
                const u16* gp = gbs[a] + (size_t)(row0s[a] + r) * K + kt + h * 8;
                u16* lp = &sm[buf][ofss[a] + c * 512];     // wave-uniform, linear dest
                __builtin_amdgcn_global_load_lds((const AS1 u32*)gp, (AS3 u32*)lp, 16, 0, 0);
            }
        }
    };

    f32x4 acc[MI][NI];
#pragma unroll
    for (int i = 0; i < MI; ++i)
#pragma unroll
        for (int j = 0; j < NI; ++j) acc[i][j] = (f32x4){0.f, 0.f, 0.f, 0.f};

    const int NT = K / 32;
    stage(0, 0);
    stage(1, 32);
    int cur = 0;
    for (int t = 0; t < NT; ++t) {
        if (t + 2 < NT) {
            int nb = cur + 2; if (nb >= 3) nb -= 3;
            stage(nb, (t + 2) * 32);
        }
        const int rem = NT - 1 - t;
        if (rem >= 2)      waitv<2 * LPW>();   // batch t landed; t+1,t+2 in flight
        else if (rem == 1) waitv<LPW>();
        else               waitv<0>();
        __builtin_amdgcn_sched_barrier(0);
        __builtin_amdgcn_s_barrier();          // tile t visible to all waves
        __builtin_amdgcn_sched_barrier(0);

        const u16* smc = sm[cur];
        short8 fah[MI], fal[MI], fbh[NI], fbl[NI];
#pragma unroll
        for (int mi = 0; mi < MI; ++mi) {
            int r = wrow * WM + mi * 16 + lr;
            int idx = r * 32 + ((lg ^ ((r >> 1) & 3)) * 8);   // swizzled read
            fah[mi] = *(const short8*)&smc[oAh + idx];
            fal[mi] = *(const short8*)&smc[oAl + idx];
        }
#pragma unroll
        for (int ni = 0; ni < NI; ++ni) {
            int r = wcol * WN + ni * 16 + lr;
            int idx = r * 32 + ((lg ^ ((r >> 1) & 3)) * 8);
            fbh[ni] = *(const short8*)&smc[oBh + idx];
            fbl[ni] = *(const short8*)&smc[oBl + idx];
        }
        // 3-product split: hh + hl + lh (ll dropped, <= 2^-18 rel)
#pragma unroll
        for (int mi = 0; mi < MI; ++mi)
#pragma unroll
            for (int ni = 0; ni < NI; ++ni) {
                acc[mi][ni] = __builtin_amdgcn_mfma_f32_16x16x32_bf16(fah[mi], fbh[ni], acc[mi][ni], 0, 0, 0);
                acc[mi][ni] = __builtin_amdgcn_mfma_f32_16x16x32_bf16(fah[mi], fbl[ni], acc[mi][ni], 0, 0, 0);
                acc[mi][ni] = __builtin_amdgcn_mfma_f32_16x16x32_bf16(fal[mi], fbh[ni], acc[mi][ni], 0, 0, 0);
            }
        __builtin_amdgcn_s_barrier();          // readers done before buf reuse
        cur = cur + 1 == 3 ? 0 : cur + 1;
    }

    // C/D layout (HW-verified, §3): col = lane&15, row = (lane>>4)*4 + v
#pragma unroll
    for (int mi = 0; mi < MI; ++mi)
#pragma unroll
        for (int ni = 0; ni < NI; ++ni) {
            int col = n0 + wcol * WN + ni * 16 + lr;
            int rbase = m0 + wrow * WM + mi * 16 + lg * 4;
            if constexpr (SCALE_EPI) {
                float s = scal[col];
#pragma unroll
                for (int v = 0; v < 4; ++v)
                    Cout[(size_t)(rbase + v) * N + col] = acc[mi][ni][v] * s;
            } else {
                float dv = Dv[col];
#pragma unroll
                for (int v = 0; v < 4; ++v) {
                    size_t o = (size_t)(rbase + v) * N + col;
                    Cout[o] = fmaf(xres[o], dv, acc[mi][ni][v]);
                }
            }
        }
}

// ---------------------------------------------------------------- scan phase A
__global__ __launch_bounds__(256)
void scan_carry(const float* __restrict__ sBu,
                const float* __restrict__ lam_re, const float* __restrict__ lam_im,
                float2* __restrict__ carry) {
    int g = blockIdx.x * 256 + threadIdx.x;
    int ch = blockIdx.y;
    const float lr = lam_re[g], li = lam_im[g];
    const float* f = sBu + (size_t)ch * CHUNK * G + g;
    float hr = 0.0f, hi = 0.0f;
    for (int tb = 0; tb < CHUNK / 8; ++tb) {
        float fb[8];
#pragma unroll
        for (int u = 0; u < 8; ++u) fb[u] = f[(size_t)(tb * 8 + u) * G];
#pragma unroll
        for (int u = 0; u < 8; ++u) {
            float nr = fmaf(lr, hr, fmaf(-li, hi, fb[u]));
            float ni = fmaf(lr, hi, li * hr);
            hr = nr; hi = ni;
        }
    }
    carry[(size_t)ch * G + g] = make_float2(hr, hi);
}

// ---------------------------------------------------------------- scan phase B (batched prefetch)
__global__ void carry_scan(const float2* __restrict__ carry,
                           const float* __restrict__ lamC_re, const float* __restrict__ lamC_im,
                           float2* __restrict__ carry_in) {
    int g = blockIdx.x * blockDim.x + threadIdx.x;
    if (g >= G) return;
    const float lr = lamC_re[g], li = lamC_im[g];
    float hr = 0.0f, hi = 0.0f;
    for (int cb = 0; cb < NCH; cb += 8) {
        float2 loc[8];
#pragma unroll
        for (int u = 0; u < 8; ++u) loc[u] = carry[(size_t)(cb + u) * G + g];
#pragma unroll
        for (int u = 0; u < 8; ++u) {
            carry_in[(size_t)(cb + u) * G + g] = make_float2(hr, hi);
            float nr = fmaf(lr, hr, -li * hi) + loc[u].x;
            float ni = fmaf(lr, hi, li * hr) + loc[u].y;
            hr = nr; hi = ni;
        }
    }
}

// ---------------------------------------------------------------- scan phase C: p = 2*Re(h) -> bf16 h/l
__global__ __launch_bounds__(256)
void scan_emit(const float* __restrict__ sBu, u16* __restrict__ ph, u16* __restrict__ pl,
               const float* __restrict__ lam_re, const float* __restrict__ lam_im,
               const float2* __restrict__ carry_in) {
    int g = blockIdx.x * 256 + threadIdx.x;
    int ch = blockIdx.y;
    const float lr = lam_re[g], li = lam_im[g];
    const float* f = sBu + (size_t)ch * CHUNK * G + g;
    u16* oh = ph + (size_t)ch * CHUNK * G + g;
    u16* ol = pl + (size_t)ch * CHUNK * G + g;
    float2 h0 = carry_in[(size_t)ch * G + g];
    float hr = h0.x, hi = h0.y;
    for (int tb = 0; tb < CHUNK / 8; ++tb) {
        float fb[8];
#pragma unroll
        for (int u = 0; u < 8; ++u) fb[u] = f[(size_t)(tb * 8 + u) * G];
#pragma unroll
        for (int u = 0; u < 8; ++u) {
            float nr = fmaf(lr, hr, fmaf(-li, hi, fb[u]));
            float ni = fmaf(lr, hi, li * hr);
            hr = nr; hi = ni;
            float p = 2.0f * hr;
            u16 hh, ll; split2(p, hh, ll);
            oh[(size_t)(tb * 8 + u) * G] = hh;
            ol[(size_t)(tb * 8 + u) * G] = ll;
        }
    }
}

// ----------------------------------------------------------------
extern "C" void kernel_launch(void* const* d_in, const int* in_sizes, int n_in,
                              void* d_out, int out_size, void* d_ws, size_t ws_size,
                              hipStream_t stream) {
    const float* x   = (const float*)d_in[0];  // (SEQ, H)
    const float* c   = (const float*)d_in[1];
    const float* kp  = (const float*)d_in[2];
    const float* kd  = (const float*)d_in[3];
    const float* dtm = (const float*)d_in[4];
    const float* B   = (const float*)d_in[5];  // (G, H)  -> GEMM1 B-operand [N=G][K=H]
    const float* Cm  = (const float*)d_in[6];  // (H, G)  -> GEMM2 B-operand [N=H][K=G]
    const float* D   = (const float*)d_in[7];
    float* out = (float*)d_out;                // (SEQ, H)

    char* w = (char*)d_ws;
    float* sBu = (float*)w;              w += (size_t)SEQ * G * 4;      // fp32 scan input
    u16* ph = (u16*)w;                   w += (size_t)SEQ * G * 2;
    u16* pl = (u16*)w;                   w += (size_t)SEQ * G * 2;
    u16* xh = (u16*)w;                   w += (size_t)SEQ * HDIM * 2;
    u16* xl = (u16*)w;                   w += (size_t)SEQ * HDIM * 2;
    u16* Bh_ = (u16*)w;                  w += (size_t)G * HDIM * 2;
    u16* Bl_ = (u16*)w;                  w += (size_t)G * HDIM * 2;
    u16* Ch_ = (u16*)w;                  w += (size_t)HDIM * G * 2;
    u16* Cl_ = (u16*)w;                  w += (size_t)HDIM * G * 2;
    float* lam_re  = (float*)w;          w += G * 4;
    float* lam_im  = (float*)w;          w += G * 4;
    float* scal    = (float*)w;          w += G * 4;
    float* lamC_re = (float*)w;          w += G * 4;
    float* lamC_im = (float*)w;          w += G * 4;
    float2* carry    = (float2*)w;       w += (size_t)NCH * G * 8;
    float2* carry_in = (float2*)w;       // total ~93 MB

    params_kernel<<<dim3(G / 256), 256, 0, stream>>>(c, kp, kd, dtm, lam_re, lam_im,
                                                     scal, lamC_re, lamC_im);
    split_all<<<dim3(2048), 256, 0, stream>>>(x, xh, xl, B, Bh_, Bl_, Cm, Ch_, Cl_);

    // sBu = (x @ B^T) * scaling   — M=8192, N=1024, K=512
    gemm_split<128, 128, 64, 64, true>
        <<<dim3(G / 128, SEQ / 128), 256, 0, stream>>>(xh, xl, Bh_, Bl_, sBu,
                                                       SEQ, G, HDIM, scal, nullptr, nullptr);

    scan_carry<<<dim3(G / 256, NCH), 256, 0, stream>>>(sBu, lam_re, lam_im, carry);
    carry_scan<<<dim3(G / 256), 256, 0, stream>>>(carry, lamC_re, lamC_im, carry_in);
    scan_emit<<<dim3(G / 256, NCH), 256, 0, stream>>>(sBu, ph, pl, lam_re, lam_im, carry_in);

    // out = p @ C^T + x*D   — M=8192, N=512, K=1024
    gemm_split<128, 64, 64, 32, false>
        <<<dim3(HDIM / 64, SEQ / 128), 256, 0, stream>>>(ph, pl, Ch_, Cl_, out,
                                                         SEQ, HDIM, G, nullptr, x, D);
}

// Round 11
// 182.349 us; speedup vs baseline: 1.0489x; 1.0489x over previous
//
#include <hip/hip_runtime.h>
#include <math.h>

// FDTD2DLayer: out = (2*Re(scan(lam2, x@B^T * scaling))) @ C^T + x*D
// m1 == 0, m3 == conj(m2) (sBu real, lam3 = conj(lam2)) => p = 2*Re(m2).
// GEMMs: bf16 2-way-split MFMA, 3-product (hh+hl+lh), fp32 accumulate.
// R10 lesson: 3-buf ring (96KB) -> 1 blk/CU killed implicit overlap (45.5us).
// This round: 2-buf (64/48KB, 2-3 blk/CU) + depth-1 COUNTED vmcnt (no drain),
// and CHUNK 64 to double scan parallelism (512 blocks, 64-step chains).

#define SEQ 8192
#define HDIM 512
#define GS 32
#define G 1024
#define CHUNK 64
#define NCH (SEQ / CHUNK)

typedef unsigned short u16;
typedef unsigned int u32;
typedef __attribute__((ext_vector_type(8))) short short8;  // 8 bf16 = 4 VGPR
typedef __attribute__((ext_vector_type(4))) float f32x4;   // MFMA C/D

#define AS1 __attribute__((address_space(1)))
#define AS3 __attribute__((address_space(3)))

__device__ __forceinline__ float softplusf(float z) {
    return fmaxf(z, 0.0f) + log1pf(expf(-fabsf(z)));
}
__device__ __forceinline__ float clipf(float v, float lo, float hi) {
    return fminf(fmaxf(v, lo), hi);
}
// split fp32 -> bf16 hi + bf16 lo; f ≈ hi + lo, |err| <= ~2^-17|f|
__device__ __forceinline__ void split2(float f, u16& h, u16& l) {
    u32 b = __float_as_uint(f);
    u32 hb = (b + 0x8000u) & 0xffff0000u;
    h = (u16)(hb >> 16);
    float r = f - __uint_as_float(hb);          // exact in fp32
    l = (u16)((__float_as_uint(r) + 0x8000u) >> 16);
}
// counted vmcnt waits (immediates only)
template<int N> __device__ __forceinline__ void waitv() {
    if constexpr (N == 0)      asm volatile("s_waitcnt vmcnt(0)" ::: "memory");
    else if constexpr (N == 6) asm volatile("s_waitcnt vmcnt(6)" ::: "memory");
    else if constexpr (N == 8) asm volatile("s_waitcnt vmcnt(8)" ::: "memory");
}

// ---------------------------------------------------------------- params (G threads)
__global__ void params_kernel(const float* __restrict__ c,
                              const float* __restrict__ kp_diag,
                              const float* __restrict__ k_diag,
                              const float* __restrict__ dt_matrix,
                              float* __restrict__ lam_re, float* __restrict__ lam_im,
                              float* __restrict__ scal,
                              float* __restrict__ lamC_re, float* __restrict__ lamC_im) {
    int g = blockIdx.x * blockDim.x + threadIdx.x;
    if (g >= G) return;
    float dt = clipf(expf(dt_matrix[g]), 0.1f, 5.0f);
    float max_c = 0.7f / dt;
    float c_pos = clipf(softplusf(c[g]), 0.01f, 0.9f * max_c);

    float kp_base = 0.0f, k_base = 0.0f;
    if (g % (GS + 1) == 0) {
        int d = g / (GS + 1);
        float kp_d = clipf(softplusf(kp_diag[d]), 1e-4f, 0.2f);
        kp_base = clipf(softplusf(kp_d), 1e-4f, 0.5f);
        float k_d = clipf(softplusf(k_diag[d]), 1e-4f, 0.2f);
        k_base = clipf(softplusf(k_d), 1e-4f, 0.5f);
    }
    float kp_full = clipf(softplusf(kp_base), 1e-4f, 0.5f);
    float k_full  = clipf(softplusf(k_base),  1e-4f, 0.5f);

    float d1 = fmaxf(1.0f + dt * k_full, 0.1f);
    float d2 = fmaxf(1.0f + dt * kp_full, 0.1f);
    float real_part = 0.5f * (1.0f / d2 + 1.0f / d1);
    float c_safe = clipf(c_pos, 0.01f, 1.0f);
    const float xi = 1.5707963267948966f;
    float imag_part = clipf(c_safe * dt * xi / sqrtf(fmaxf(d1 * d2, 1e-6f)), -10.0f, 10.0f);

    lam_re[g] = real_part;
    lam_im[g] = imag_part;
    scal[g] = 1.0f / (1.0f + dt * kp_full);

    float ar = real_part, ai = imag_part;       // lambda^CHUNK (64 = 2^6) by squaring
#pragma unroll
    for (int s = 0; s < 6; ++s) {
        float nr = ar * ar - ai * ai;
        float ni = 2.0f * ar * ai;
        ar = nr; ai = ni;
    }
    lamC_re[g] = ar; lamC_im[g] = ai;
}

// ---------------------------------------------------------------- fused fp32 -> (bf16h, bf16l) for x, B, Cm
#define N4X (SEQ * HDIM / 4)
#define N4B (G * HDIM / 4)
#define N4C (HDIM * G / 4)
__global__ __launch_bounds__(256)
void split_all(const float* __restrict__ x,  u16* __restrict__ xh,  u16* __restrict__ xl,
               const float* __restrict__ B,  u16* __restrict__ Bh,  u16* __restrict__ Bl,
               const float* __restrict__ Cm, u16* __restrict__ Ch,  u16* __restrict__ Cl) {
    int stride = gridDim.x * 256;
    for (int i = blockIdx.x * 256 + threadIdx.x; i < N4X + N4B + N4C; i += stride) {
        const float* in; u16* hi; u16* lo; int j = i;
        if (j < N4X) { in = x; hi = xh; lo = xl; }
        else if (j < N4X + N4B) { j -= N4X; in = B; hi = Bh; lo = Bl; }
        else { j -= N4X + N4B; in = Cm; hi = Ch; lo = Cl; }
        float4 v = ((const float4*)in)[j];
        ushort4 h, l;
        split2(v.x, h.x, l.x); split2(v.y, h.y, l.y);
        split2(v.z, h.z, l.z); split2(v.w, h.w, l.w);
        ((ushort4*)hi)[j] = h;
        ((ushort4*)lo)[j] = l;
    }
}

// ---------------------------------------------------------------- split-bf16 MFMA GEMM
// Cout[M,N] = (Ah+Al)[M,K] * (Bh+Bl)[N,K]^T   (bf16 row-major, K-contig)
// 2x2 waves of WMxWN; BK=32; 2-buffer double-buffer + depth-1 COUNTED vmcnt:
// stage(t+1); waitv<LPW> [t landed, t+1 in flight]; s_barrier; ds_read+MFMA;
// s_barrier. Keeps 2-3 blocks/CU implicit overlap (R10 lesson) AND avoids the
// vmcnt(0) drain. LDS swizzle (R7: 0 bank conflicts) on global source +
// ds_read index, LDS dest linear (rule #21). T1 XCD swizzle (R8: -20us).
template<int BM, int BN, int WM, int WN, bool SCALE_EPI, int MINW>
__global__ __launch_bounds__(256, MINW)
void gemm_split(const u16* __restrict__ Ah, const u16* __restrict__ Al,
                const u16* __restrict__ Bh, const u16* __restrict__ Bl,
                float* __restrict__ Cout, int M, int N, int K,
                const float* __restrict__ scal,
                const float* __restrict__ xres, const float* __restrict__ Dv) {
    constexpr int MI = WM / 16, NI = WN / 16;
    constexpr int ACH = BM / 16, BCH = BN / 16;            // 1KB chunks (16 rows x 32 u16)
    constexpr int oAh = 0, oAl = BM * 32;
    constexpr int oBh = 2 * BM * 32, oBl = 2 * BM * 32 + BN * 32;
    constexpr int BUFS = 2 * BM * 32 + 2 * BN * 32;        // u16 per buffer
    constexpr int LPW = (ACH + BCH) / 2;                   // global_load_lds per wave per stage
    __shared__ __align__(16) u16 sm[2][BUFS];

    const int tid = threadIdx.x;
    const int lane = tid & 63, wid = tid >> 6;
    const int wrow = wid >> 1, wcol = wid & 1;
    const int lr = lane & 15, lg = lane >> 4;

    // T1: bijective XCD swizzle (nwg % 8 == 0 for both grids: 512)
    const int flat = blockIdx.y * gridDim.x + blockIdx.x;
    const int cpx = (gridDim.x * gridDim.y) >> 3;
    const int swz = (flat & 7) * cpx + (flat >> 3);
    const int m0 = (swz / gridDim.x) * BM, n0 = (swz % gridDim.x) * BN;

    const u16* gbs[4]   = {Ah, Al, Bh, Bl};
    const int  nchs[4]  = {ACH, ACH, BCH, BCH};
    const int  row0s[4] = {m0, m0, n0, n0};
    const int  ofss[4]  = {oAh, oAl, oBh, oBl};

    const int srow = lane >> 2;        // row-in-chunk 0..15
    const int shp  = lane & 3;         // physical 16B slot in row

    auto stage = [&](int buf, int kt) {
#pragma unroll
        for (int a = 0; a < 4; ++a) {
            for (int c = wid; c < nchs[a]; c += 4) {
                int r = c * 16 + srow;
                int h = shp ^ ((r >> 1) & 3);              // inverse swizzle on source
                const u16* gp = gbs[a] + (size_t)(row0s[a] + r) * K + kt + h * 8;
                u16* lp = &sm[buf][ofss[a] + c * 512];     // wave-uniform, linear dest
                __builtin_amdgcn_global_load_lds((const AS1 u32*)gp, (AS3 u32*)lp, 16, 0, 0);
            }
        }
    };

    f32x4 acc[MI][NI];
#pragma unroll
    for (int i = 0; i < MI; ++i)
#pragma unroll
        for (int j = 0; j < NI; ++j) acc[i][j] = (f32x4){0.f, 0.f, 0.f, 0.f};

    const int NT = K / 32;
    stage(0, 0);
    for (int t = 0; t < NT; ++t) {
        const int buf = t & 1;
        if (t + 1 < NT) {
            stage(buf ^ 1, (t + 1) * 32);
            waitv<LPW>();                      // tile t landed; t+1 stays in flight
        } else {
            waitv<0>();                        // tail drain
        }
        __builtin_amdgcn_sched_barrier(0);
        __builtin_amdgcn_s_barrier();          // tile t visible to all waves
        __builtin_amdgcn_sched_barrier(0);

        const u16* smc = sm[buf];
        short8 fah[MI], fal[MI], fbh[NI], fbl[NI];
#pragma unroll
        for (int mi = 0; mi < MI; ++mi) {
            int r = wrow * WM + mi * 16 + lr;
            int idx = r * 32 + ((lg ^ ((r >> 1) & 3)) * 8);   // swizzled read
            fah[mi] = *(const short8*)&smc[oAh + idx];
            fal[mi] = *(const short8*)&smc[oAl + idx];
        }
#pragma unroll
        for (int ni = 0; ni < NI; ++ni) {
            int r = wcol * WN + ni * 16 + lr;
            int idx = r * 32 + ((lg ^ ((r >> 1) & 3)) * 8);
            fbh[ni] = *(const short8*)&smc[oBh + idx];
            fbl[ni] = *(const short8*)&smc[oBl + idx];
        }
        // 3-product split: hh + hl + lh (ll dropped, <= 2^-18 rel)
#pragma unroll
        for (int mi = 0; mi < MI; ++mi)
#pragma unroll
            for (int ni = 0; ni < NI; ++ni) {
                acc[mi][ni] = __builtin_amdgcn_mfma_f32_16x16x32_bf16(fah[mi], fbh[ni], acc[mi][ni], 0, 0, 0);
                acc[mi][ni] = __builtin_amdgcn_mfma_f32_16x16x32_bf16(fah[mi], fbl[ni], acc[mi][ni], 0, 0, 0);
                acc[mi][ni] = __builtin_amdgcn_mfma_f32_16x16x32_bf16(fal[mi], fbh[ni], acc[mi][ni], 0, 0, 0);
            }
        __builtin_amdgcn_s_barrier();          // readers done before buf^1 reuse
    }

    // C/D layout (HW-verified, §3): col = lane&15, row = (lane>>4)*4 + v
#pragma unroll
    for (int mi = 0; mi < MI; ++mi)
#pragma unroll
        for (int ni = 0; ni < NI; ++ni) {
            int col = n0 + wcol * WN + ni * 16 + lr;
            int rbase = m0 + wrow * WM + mi * 16 + lg * 4;
            if constexpr (SCALE_EPI) {
                float s = scal[col];
#pragma unroll
                for (int v = 0; v < 4; ++v)
                    Cout[(size_t)(rbase + v) * N + col] = acc[mi][ni][v] * s;
            } else {
                float dv = Dv[col];
#pragma unroll
                for (int v = 0; v < 4; ++v) {
                    size_t o = (size_t)(rbase + v) * N + col;
                    Cout[o] = fmaf(xres[o], dv, acc[mi][ni][v]);
                }
            }
        }
}

// ---------------------------------------------------------------- scan phase A (CHUNK=64, 512 blocks)
__global__ __launch_bounds__(256)
void scan_carry(const float* __restrict__ sBu,
                const float* __restrict__ lam_re, const float* __restrict__ lam_im,
                float2* __restrict__ carry) {
    int g = blockIdx.x * 256 + threadIdx.x;
    int ch = blockIdx.y;
    const float lr = lam_re[g], li = lam_im[g];
    const float* f = sBu + (size_t)ch * CHUNK * G + g;
    float hr = 0.0f, hi = 0.0f;
    for (int tb = 0; tb < CHUNK / 8; ++tb) {
        float fb[8];
#pragma unroll
        for (int u = 0; u < 8; ++u) fb[u] = f[(size_t)(tb * 8 + u) * G];
#pragma unroll
        for (int u = 0; u < 8; ++u) {
            float nr = fmaf(lr, hr, fmaf(-li, hi, fb[u]));
            float ni = fmaf(lr, hi, li * hr);
            hr = nr; hi = ni;
        }
    }
    carry[(size_t)ch * G + g] = make_float2(hr, hi);
}

// ---------------------------------------------------------------- scan phase B (batched prefetch)
__global__ void carry_scan(const float2* __restrict__ carry,
                           const float* __restrict__ lamC_re, const float* __restrict__ lamC_im,
                           float2* __restrict__ carry_in) {
    int g = blockIdx.x * blockDim.x + threadIdx.x;
    if (g >= G) return;
    const float lr = lamC_re[g], li = lamC_im[g];
    float hr = 0.0f, hi = 0.0f;
    for (int cb = 0; cb < NCH; cb += 8) {
        float2 loc[8];
#pragma unroll
        for (int u = 0; u < 8; ++u) loc[u] = carry[(size_t)(cb + u) * G + g];
#pragma unroll
        for (int u = 0; u < 8; ++u) {
            carry_in[(size_t)(cb + u) * G + g] = make_float2(hr, hi);
            float nr = fmaf(lr, hr, -li * hi) + loc[u].x;
            float ni = fmaf(lr, hi, li * hr) + loc[u].y;
            hr = nr; hi = ni;
        }
    }
}

// ---------------------------------------------------------------- scan phase C: p = 2*Re(h) -> bf16 h/l
__global__ __launch_bounds__(256)
void scan_emit(const float* __restrict__ sBu, u16* __restrict__ ph, u16* __restrict__ pl,
               const float* __restrict__ lam_re, const float* __restrict__ lam_im,
               const float2* __restrict__ carry_in) {
    int g = blockIdx.x * 256 + threadIdx.x;
    int ch = blockIdx.y;
    const float lr = lam_re[g], li = lam_im[g];
    const float* f = sBu + (size_t)ch * CHUNK * G + g;
    u16* oh = ph + (size_t)ch * CHUNK * G + g;
    u16* ol = pl + (size_t)ch * CHUNK * G + g;
    float2 h0 = carry_in[(size_t)ch * G + g];
    float hr = h0.x, hi = h0.y;
    for (int tb = 0; tb < CHUNK / 8; ++tb) {
        float fb[8];
#pragma unroll
        for (int u = 0; u < 8; ++u) fb[u] = f[(size_t)(tb * 8 + u) * G];
#pragma unroll
        for (int u = 0; u < 8; ++u) {
            float nr = fmaf(lr, hr, fmaf(-li, hi, fb[u]));
            float ni = fmaf(lr, hi, li * hr);
            hr = nr; hi = ni;
            float p = 2.0f * hr;
            u16 hh, ll; split2(p, hh, ll);
            oh[(size_t)(tb * 8 + u) * G] = hh;
            ol[(size_t)(tb * 8 + u) * G] = ll;
        }
    }
}

// ----------------------------------------------------------------
extern "C" void kernel_launch(void* const* d_in, const int* in_sizes, int n_in,
                              void* d_out, int out_size, void* d_ws, size_t ws_size,
                              hipStream_t stream) {
    const float* x   = (const float*)d_in[0];  // (SEQ, H)
    const float* c   = (const float*)d_in[1];
    const float* kp  = (const float*)d_in[2];
    const float* kd  = (const float*)d_in[3];
    const float* dtm = (const float*)d_in[4];
    const float* B   = (const float*)d_in[5];  // (G, H)  -> GEMM1 B-operand [N=G][K=H]
    const float* Cm  = (const float*)d_in[6];  // (H, G)  -> GEMM2 B-operand [N=H][K=G]
    const float* D   = (const float*)d_in[7];
    float* out = (float*)d_out;                // (SEQ, H)

    char* w = (char*)d_ws;
    float* sBu = (float*)w;              w += (size_t)SEQ * G * 4;      // fp32 scan input
    u16* ph = (u16*)w;                   w += (size_t)SEQ * G * 2;
    u16* pl = (u16*)w;                   w += (size_t)SEQ * G * 2;
    u16* xh = (u16*)w;                   w += (size_t)SEQ * HDIM * 2;
    u16* xl = (u16*)w;                   w += (size_t)SEQ * HDIM * 2;
    u16* Bh_ = (u16*)w;                  w += (size_t)G * HDIM * 2;
    u16* Bl_ = (u16*)w;                  w += (size_t)G * HDIM * 2;
    u16* Ch_ = (u16*)w;                  w += (size_t)HDIM * G * 2;
    u16* Cl_ = (u16*)w;                  w += (size_t)HDIM * G * 2;
    float* lam_re  = (float*)w;          w += G * 4;
    float* lam_im  = (float*)w;          w += G * 4;
    float* scal    = (float*)w;          w += G * 4;
    float* lamC_re = (float*)w;          w += G * 4;
    float* lamC_im = (float*)w;          w += G * 4;
    float2* carry    = (float2*)w;       w += (size_t)NCH * G * 8;
    float2* carry_in = (float2*)w;       // total ~95 MB

    params_kernel<<<dim3(G / 256), 256, 0, stream>>>(c, kp, kd, dtm, lam_re, lam_im,
                                                     scal, lamC_re, lamC_im);
    split_all<<<dim3(2048), 256, 0, stream>>>(x, xh, xl, B, Bh_, Bl_, Cm, Ch_, Cl_);

    // sBu = (x @ B^T) * scaling   — M=8192, N=1024, K=512
    gemm_split<128, 128, 64, 64, true, 2>
        <<<dim3(G / 128, SEQ / 128), 256, 0, stream>>>(xh, xl, Bh_, Bl_, sBu,
                                                       SEQ, G, HDIM, scal, nullptr, nullptr);

    scan_carry<<<dim3(G / 256, NCH), 256, 0, stream>>>(sBu, lam_re, lam_im, carry);
    carry_scan<<<dim3(G / 256), 256, 0, stream>>>(carry, lamC_re, lamC_im, carry_in);
    scan_emit<<<dim3(G / 256, NCH), 256, 0, stream>>>(sBu, ph, pl, lam_re, lam_im, carry_in);

    // out = p @ C^T + x*D   — M=8192, N=512, K=1024; 48KB LDS -> 3 blocks/CU
    gemm_split<128, 64, 64, 32, false, 3>
        <<<dim3(HDIM / 64, SEQ / 128), 256, 0, stream>>>(ph, pl, Ch_, Cl_, out,
                                                         SEQ, HDIM, G, nullptr, x, D);
}

// Round 13
// 173.119 us; speedup vs baseline: 1.1048x; 1.0533x over previous
//
#include <hip/hip_runtime.h>
#include <math.h>

// FDTD2DLayer: out = (2*Re(scan(lam2, x@B^T * scaling))) @ C^T + x*D
// m1 == 0, m3 == conj(m2) (sBu real, lam3 = conj(lam2)) => p = 2*Re(m2).
// GEMMs: bf16 2-way-split MFMA, 3-product (hh+hl+lh), fp32 accumulate.
// R11: 182.3us. This round: scan phase-A fused into GEMM1's epilogue
// (CHUNK=128=BM: each block owns one (chunk x 128-col) sBu tile; local carry
// computed from the acc tile staged into the dead 64KB staging LDS), float4
// sBu write, scan_carry kernel deleted (-32MB HBM, -1 launch).

#define SEQ 8192
#define HDIM 512
#define GS 32
#define G 1024
#define CHUNK 128
#define NCH (SEQ / CHUNK)

typedef unsigned short u16;
typedef unsigned int u32;
typedef __attribute__((ext_vector_type(8))) short short8;  // 8 bf16 = 4 VGPR
typedef __attribute__((ext_vector_type(4))) float f32x4;   // MFMA C/D

#define AS1 __attribute__((address_space(1)))
#define AS3 __attribute__((address_space(3)))

__device__ __forceinline__ float softplusf(float z) {
    return fmaxf(z, 0.0f) + log1pf(expf(-fabsf(z)));
}
__device__ __forceinline__ float clipf(float v, float lo, float hi) {
    return fminf(fmaxf(v, lo), hi);
}
// split fp32 -> bf16 hi + bf16 lo; f ≈ hi + lo, |err| <= ~2^-17|f|
__device__ __forceinline__ void split2(float f, u16& h, u16& l) {
    u32 b = __float_as_uint(f);
    u32 hb = (b + 0x8000u) & 0xffff0000u;
    h = (u16)(hb >> 16);
    float r = f - __uint_as_float(hb);          // exact in fp32
    l = (u16)((__float_as_uint(r) + 0x8000u) >> 16);
}
// counted vmcnt waits (immediates only)
template<int N> __device__ __forceinline__ void waitv() {
    if constexpr (N == 0)      asm volatile("s_waitcnt vmcnt(0)" ::: "memory");
    else if constexpr (N == 6) asm volatile("s_waitcnt vmcnt(6)" ::: "memory");
    else if constexpr (N == 8) asm volatile("s_waitcnt vmcnt(8)" ::: "memory");
}

// ---------------------------------------------------------------- params (G threads)
__global__ void params_kernel(const float* __restrict__ c,
                              const float* __restrict__ kp_diag,
                              const float* __restrict__ k_diag,
                              const float* __restrict__ dt_matrix,
                              float* __restrict__ lam_re, float* __restrict__ lam_im,
                              float* __restrict__ scal,
                              float* __restrict__ lamC_re, float* __restrict__ lamC_im) {
    int g = blockIdx.x * blockDim.x + threadIdx.x;
    if (g >= G) return;
    float dt = clipf(expf(dt_matrix[g]), 0.1f, 5.0f);
    float max_c = 0.7f / dt;
    float c_pos = clipf(softplusf(c[g]), 0.01f, 0.9f * max_c);

    float kp_base = 0.0f, k_base = 0.0f;
    if (g % (GS + 1) == 0) {
        int d = g / (GS + 1);
        float kp_d = clipf(softplusf(kp_diag[d]), 1e-4f, 0.2f);
        kp_base = clipf(softplusf(kp_d), 1e-4f, 0.5f);
        float k_d = clipf(softplusf(k_diag[d]), 1e-4f, 0.2f);
        k_base = clipf(softplusf(k_d), 1e-4f, 0.5f);
    }
    float kp_full = clipf(softplusf(kp_base), 1e-4f, 0.5f);
    float k_full  = clipf(softplusf(k_base),  1e-4f, 0.5f);

    float d1 = fmaxf(1.0f + dt * k_full, 0.1f);
    float d2 = fmaxf(1.0f + dt * kp_full, 0.1f);
    float real_part = 0.5f * (1.0f / d2 + 1.0f / d1);
    float c_safe = clipf(c_pos, 0.01f, 1.0f);
    const float xi = 1.5707963267948966f;
    float imag_part = clipf(c_safe * dt * xi / sqrtf(fmaxf(d1 * d2, 1e-6f)), -10.0f, 10.0f);

    lam_re[g] = real_part;
    lam_im[g] = imag_part;
    scal[g] = 1.0f / (1.0f + dt * kp_full);

    float ar = real_part, ai = imag_part;       // lambda^CHUNK (128 = 2^7) by squaring
#pragma unroll
    for (int s = 0; s < 7; ++s) {
        float nr = ar * ar - ai * ai;
        float ni = 2.0f * ar * ai;
        ar = nr; ai = ni;
    }
    lamC_re[g] = ar; lamC_im[g] = ai;
}

// ---------------------------------------------------------------- fused fp32 -> (bf16h, bf16l) for x, B, Cm
#define N4X (SEQ * HDIM / 4)
#define N4B (G * HDIM / 4)
#define N4C (HDIM * G / 4)
__global__ __launch_bounds__(256)
void split_all(const float* __restrict__ x,  u16* __restrict__ xh,  u16* __restrict__ xl,
               const float* __restrict__ B,  u16* __restrict__ Bh,  u16* __restrict__ Bl,
               const float* __restrict__ Cm, u16* __restrict__ Ch,  u16* __restrict__ Cl) {
    int stride = gridDim.x * 256;
    for (int i = blockIdx.x * 256 + threadIdx.x; i < N4X + N4B + N4C; i += stride) {
        const float* in; u16* hi; u16* lo; int j = i;
        if (j < N4X) { in = x; hi = xh; lo = xl; }
        else if (j < N4X + N4B) { j -= N4X; in = B; hi = Bh; lo = Bl; }
        else { j -= N4X + N4B; in = Cm; hi = Ch; lo = Cl; }
        float4 v = ((const float4*)in)[j];
        ushort4 h, l;
        split2(v.x, h.x, l.x); split2(v.y, h.y, l.y);
        split2(v.z, h.z, l.z); split2(v.w, h.w, l.w);
        ((ushort4*)hi)[j] = h;
        ((ushort4*)lo)[j] = l;
    }
}

// ---------------------------------------------------------------- split-bf16 MFMA GEMM
// Cout[M,N] = (Ah+Al)[M,K] * (Bh+Bl)[N,K]^T   (bf16 row-major, K-contig)
// 2x2 waves of WMxWN; BK=32; 2-buffer dbuf + depth-1 COUNTED vmcnt (R11).
// LDS swizzle (R7: 0 bank conflicts) on global source + ds_read index,
// LDS dest linear (rule #21). T1 XCD swizzle (R8: -20us).
// SCALE_EPI=true (GEMM1): fused epilogue — acc*scal -> dead staging LDS as
// 128x128 fp32; waves 0-1 compute the chunk-local scan carry (scan phase A),
// waves 2-3 do the float4-coalesced sBu global write. CHUNK==BM required.
template<int BM, int BN, int WM, int WN, bool SCALE_EPI, int MINW>
__global__ __launch_bounds__(256, MINW)
void gemm_split(const u16* __restrict__ Ah, const u16* __restrict__ Al,
                const u16* __restrict__ Bh, const u16* __restrict__ Bl,
                float* __restrict__ Cout, int M, int N, int K,
                const float* __restrict__ scal,
                const float* __restrict__ xres, const float* __restrict__ Dv,
                const float* __restrict__ lam_re, const float* __restrict__ lam_im,
                float2* __restrict__ carry_out) {
    constexpr int MI = WM / 16, NI = WN / 16;
    constexpr int ACH = BM / 16, BCH = BN / 16;            // 1KB chunks (16 rows x 32 u16)
    constexpr int oAh = 0, oAl = BM * 32;
    constexpr int oBh = 2 * BM * 32, oBl = 2 * BM * 32 + BN * 32;
    constexpr int BUFS = 2 * BM * 32 + 2 * BN * 32;        // u16 per buffer
    constexpr int LPW = (ACH + BCH) / 2;                   // global_load_lds per wave per stage
    __shared__ __align__(16) u16 sm[2][BUFS];

    const int tid = threadIdx.x;
    const int lane = tid & 63, wid = tid >> 6;
    const int wrow = wid >> 1, wcol = wid & 1;
    const int lr = lane & 15, lg = lane >> 4;

    // T1: bijective XCD swizzle (nwg % 8 == 0 for both grids: 512)
    const int flat = blockIdx.y * gridDim.x + blockIdx.x;
    const int cpx = (gridDim.x * gridDim.y) >> 3;
    const int swz = (flat & 7) * cpx + (flat >> 3);
    const int m0 = (swz / gridDim.x) * BM, n0 = (swz % gridDim.x) * BN;

    const u16* gbs[4]   = {Ah, Al, Bh, Bl};
    const int  nchs[4]  = {ACH, ACH, BCH, BCH};
    const int  row0s[4] = {m0, m0, n0, n0};
    const int  ofss[4]  = {oAh, oAl, oBh, oBl};

    const int srow = lane >> 2;        // row-in-chunk 0..15
    const int shp  = lane & 3;         // physical 16B slot in row

    auto stage = [&](int buf, int kt) {
#pragma unroll
        for (int a = 0; a < 4; ++a) {
            for (int c = wid; c < nchs[a]; c += 4) {
                int r = c * 16 + srow;
                int h = shp ^ ((r >> 1) & 3);              // inverse swizzle on source
                const u16* gp = gbs[a] + (size_t)(row0s[a] + r) * K + kt + h * 8;
                u16* lp = &sm[buf][ofss[a] + c * 512];     // wave-uniform, linear dest
                __builtin_amdgcn_global_load_lds((const AS1 u32*)gp, (AS3 u32*)lp, 16, 0, 0);
            }
        }
    };

    f32x4 acc[MI][NI];
#pragma unroll
    for (int i = 0; i < MI; ++i)
#pragma unroll
        for (int j = 0; j < NI; ++j) acc[i][j] = (f32x4){0.f, 0.f, 0.f, 0.f};

    const int NT = K / 32;
    stage(0, 0);
    for (int t = 0; t < NT; ++t) {
        const int buf = t & 1;
        if (t + 1 < NT) {
            stage(buf ^ 1, (t + 1) * 32);
            waitv<LPW>();                      // tile t landed; t+1 stays in flight
        } else {
            waitv<0>();                        // tail drain
        }
        __builtin_amdgcn_sched_barrier(0);
        __builtin_amdgcn_s_barrier();          // tile t visible to all waves
        __builtin_amdgcn_sched_barrier(0);

        const u16* smc = sm[buf];
        short8 fah[MI], fal[MI], fbh[NI], fbl[NI];
#pragma unroll
        for (int mi = 0; mi < MI; ++mi) {
            int r = wrow * WM + mi * 16 + lr;
            int idx = r * 32 + ((lg ^ ((r >> 1) & 3)) * 8);   // swizzled read
            fah[mi] = *(const short8*)&smc[oAh + idx];
            fal[mi] = *(const short8*)&smc[oAl + idx];
        }
#pragma unroll
        for (int ni = 0; ni < NI; ++ni) {
            int r = wcol * WN + ni * 16 + lr;
            int idx = r * 32 + ((lg ^ ((r >> 1) & 3)) * 8);
            fbh[ni] = *(const short8*)&smc[oBh + idx];
            fbl[ni] = *(const short8*)&smc[oBl + idx];
        }
        // 3-product split: hh + hl + lh (ll dropped, <= 2^-18 rel)
#pragma unroll
        for (int mi = 0; mi < MI; ++mi)
#pragma unroll
            for (int ni = 0; ni < NI; ++ni) {
                acc[mi][ni] = __builtin_amdgcn_mfma_f32_16x16x32_bf16(fah[mi], fbh[ni], acc[mi][ni], 0, 0, 0);
                acc[mi][ni] = __builtin_amdgcn_mfma_f32_16x16x32_bf16(fah[mi], fbl[ni], acc[mi][ni], 0, 0, 0);
                acc[mi][ni] = __builtin_amdgcn_mfma_f32_16x16x32_bf16(fal[mi], fbh[ni], acc[mi][ni], 0, 0, 0);
            }
        __builtin_amdgcn_s_barrier();          // readers done before buf^1 reuse
    }

    // C/D layout (HW-verified, §3): col = lane&15, row = (lane>>4)*4 + v
    if constexpr (SCALE_EPI) {
        // ---- fused scan-phase-A epilogue (CHUNK == BM == 128, BN == 128) ----
        float* smf = (float*)&sm[0][0];        // 128x128 fp32 = 64KB (staging is dead)
#pragma unroll
        for (int mi = 0; mi < MI; ++mi)
#pragma unroll
            for (int ni = 0; ni < NI; ++ni) {
                int col = wcol * WN + ni * 16 + lr;
                int rbase = wrow * WM + mi * 16 + lg * 4;
#pragma unroll
                for (int v = 0; v < 4; ++v)
                    smf[(rbase + v) * BM + col] = acc[mi][ni][v];
            }
        __syncthreads();
        if (tid < 128) {
            // waves 0-1: per-column 128-step scan (batch-8 LDS reads)
            int col = tid;
            float s  = scal[n0 + col];
            float lre = lam_re[n0 + col], lim = lam_im[n0 + col];
            float hr = 0.0f, hi = 0.0f;
            for (int b = 0; b < BM / 8; ++b) {
                float fb[8];
#pragma unroll
                for (int u = 0; u < 8; ++u) fb[u] = smf[(b * 8 + u) * BM + col] * s;
#pragma unroll
                for (int u = 0; u < 8; ++u) {
                    float nr = fmaf(lre, hr, fmaf(-lim, hi, fb[u]));
                    float ni = fmaf(lre, hi, lim * hr);
                    hr = nr; hi = ni;
                }
            }
            carry_out[(size_t)(m0 >> 7) * N + n0 + col] = make_float2(hr, hi);
        } else {
            // waves 2-3: float4-coalesced scaled sBu write
            int t = tid - 128;
            int c4 = t & 31, rg = t >> 5;      // 32 col-quads x 4 row-groups
            float4 s4 = *(const float4*)&scal[n0 + c4 * 4];
            for (int it = 0; it < BM / 4; ++it) {
                int r = it * 4 + rg;
                float4 v4 = *(float4*)&smf[r * BM + c4 * 4];
                v4.x *= s4.x; v4.y *= s4.y; v4.z *= s4.z; v4.w *= s4.w;
                *(float4*)&Cout[(size_t)(m0 + r) * N + n0 + c4 * 4] = v4;
            }
        }
    } else {
#pragma unroll
        for (int mi = 0; mi < MI; ++mi)
#pragma unroll
            for (int ni = 0; ni < NI; ++ni) {
                int col = n0 + wcol * WN + ni * 16 + lr;
                int rbase = m0 + wrow * WM + mi * 16 + lg * 4;
                float dv = Dv[col];
#pragma unroll
                for (int v = 0; v < 4; ++v) {
                    size_t o = (size_t)(rbase + v) * N + col;
                    Cout[o] = fmaf(xres[o], dv, acc[mi][ni][v]);
                }
            }
    }
}

// ---------------------------------------------------------------- scan phase B (batched prefetch)
__global__ void carry_scan(const float2* __restrict__ carry,
                           const float* __restrict__ lamC_re, const float* __restrict__ lamC_im,
                           float2* __restrict__ carry_in) {
    int g = blockIdx.x * blockDim.x + threadIdx.x;
    if (g >= G) return;
    const float lr = lamC_re[g], li = lamC_im[g];
    float hr = 0.0f, hi = 0.0f;
    for (int cb = 0; cb < NCH; cb += 8) {
        float2 loc[8];
#pragma unroll
        for (int u = 0; u < 8; ++u) loc[u] = carry[(size_t)(cb + u) * G + g];
#pragma unroll
        for (int u = 0; u < 8; ++u) {
            carry_in[(size_t)(cb + u) * G + g] = make_float2(hr, hi);
            float nr = fmaf(lr, hr, -li * hi) + loc[u].x;
            float ni = fmaf(lr, hi, li * hr) + loc[u].y;
            hr = nr; hi = ni;
        }
    }
}

// ---------------------------------------------------------------- scan phase C: p = 2*Re(h) -> bf16 h/l
__global__ __launch_bounds__(256)
void scan_emit(const float* __restrict__ sBu, u16* __restrict__ ph, u16* __restrict__ pl,
               const float* __restrict__ lam_re, const float* __restrict__ lam_im,
               const float2* __restrict__ carry_in) {
    int g = blockIdx.x * 256 + threadIdx.x;
    int ch = blockIdx.y;
    const float lr = lam_re[g], li = lam_im[g];
    const float* f = sBu + (size_t)ch * CHUNK * G + g;
    u16* oh = ph + (size_t)ch * CHUNK * G + g;
    u16* ol = pl + (size_t)ch * CHUNK * G + g;
    float2 h0 = carry_in[(size_t)ch * G + g];
    float hr = h0.x, hi = h0.y;
    for (int tb = 0; tb < CHUNK / 8; ++tb) {
        float fb[8];
#pragma unroll
        for (int u = 0; u < 8; ++u) fb[u] = f[(size_t)(tb * 8 + u) * G];
#pragma unroll
        for (int u = 0; u < 8; ++u) {
            float nr = fmaf(lr, hr, fmaf(-li, hi, fb[u]));
            float ni = fmaf(lr, hi, li * hr);
            hr = nr; hi = ni;
            float p = 2.0f * hr;
            u16 hh, ll; split2(p, hh, ll);
            oh[(size_t)(tb * 8 + u) * G] = hh;
            ol[(size_t)(tb * 8 + u) * G] = ll;
        }
    }
}

// ----------------------------------------------------------------
extern "C" void kernel_launch(void* const* d_in, const int* in_sizes, int n_in,
                              void* d_out, int out_size, void* d_ws, size_t ws_size,
                              hipStream_t stream) {
    const float* x   = (const float*)d_in[0];  // (SEQ, H)
    const float* c   = (const float*)d_in[1];
    const float* kp  = (const float*)d_in[2];
    const float* kd  = (const float*)d_in[3];
    const float* dtm = (const float*)d_in[4];
    const float* B   = (const float*)d_in[5];  // (G, H)  -> GEMM1 B-operand [N=G][K=H]
    const float* Cm  = (const float*)d_in[6];  // (H, G)  -> GEMM2 B-operand [N=H][K=G]
    const float* D   = (const float*)d_in[7];
    float* out = (float*)d_out;                // (SEQ, H)

    char* w = (char*)d_ws;
    float* sBu = (float*)w;              w += (size_t)SEQ * G * 4;      // fp32 scan input
    u16* ph = (u16*)w;                   w += (size_t)SEQ * G * 2;
    u16* pl = (u16*)w;                   w += (size_t)SEQ * G * 2;
    u16* xh = (u16*)w;                   w += (size_t)SEQ * HDIM * 2;
    u16* xl = (u16*)w;                   w += (size_t)SEQ * HDIM * 2;
    u16* Bh_ = (u16*)w;                  w += (size_t)G * HDIM * 2;
    u16* Bl_ = (u16*)w;                  w += (size_t)G * HDIM * 2;
    u16* Ch_ = (u16*)w;                  w += (size_t)HDIM * G * 2;
    u16* Cl_ = (u16*)w;                  w += (size_t)HDIM * G * 2;
    float* lam_re  = (float*)w;          w += G * 4;
    float* lam_im  = (float*)w;          w += G * 4;
    float* scal    = (float*)w;          w += G * 4;
    float* lamC_re = (float*)w;          w += G * 4;
    float* lamC_im = (float*)w;          w += G * 4;
    float2* carry    = (float2*)w;       w += (size_t)NCH * G * 8;
    float2* carry_in = (float2*)w;       // total ~94 MB

    params_kernel<<<dim3(G / 256), 256, 0, stream>>>(c, kp, kd, dtm, lam_re, lam_im,
                                                     scal, lamC_re, lamC_im);
    split_all<<<dim3(2048), 256, 0, stream>>>(x, xh, xl, B, Bh_, Bl_, Cm, Ch_, Cl_);

    // sBu = (x @ B^T) * scaling + chunk-local carries   — M=8192, N=1024, K=512
    gemm_split<128, 128, 64, 64, true, 2>
        <<<dim3(G / 128, SEQ / 128), 256, 0, stream>>>(xh, xl, Bh_, Bl_, sBu,
                                                       SEQ, G, HDIM, scal, nullptr, nullptr,
                                                       lam_re, lam_im, carry);

    carry_scan<<<dim3(G / 256), 256, 0, stream>>>(carry, lamC_re, lamC_im, carry_in);
    scan_emit<<<dim3(G / 256, NCH), 256, 0, stream>>>(sBu, ph, pl, lam_re, lam_im, carry_in);

    // out = p @ C^T + x*D   — M=8192, N=512, K=1024; 48KB LDS -> 3 blocks/CU
    gemm_split<128, 64, 64, 32, false, 3>
        <<<dim3(HDIM / 64, SEQ / 128), 256, 0, stream>>>(ph, pl, Ch_, Cl_, out,
                                                         SEQ, HDIM, G, nullptr, x, D,
                                                         nullptr, nullptr, nullptr);
}